// Round 3
// baseline (77.174 us; speedup 1.0000x reference)
//
#include <hip/hip_runtime.h>

#define EPSF 1e-6f
#define L2E  1.44269504088896340736f   // log2(e)

typedef float v2f __attribute__((ext_vector_type(2)));

constexpr int NT      = 256;
constexpr int TILE    = 64;                  // q columns per block
constexpr int RPT     = 4;                   // z rows per thread
constexpr int ROWS_PB = NT * RPT;            // 1024 rows per block
constexpr int RBLK    = 16384 / ROWS_PB;     // 16
constexpr int CBLK    = 8192 / TILE;         // 128
constexpr int NB      = RBLK * CBLK;         // 2048 blocks total (8/CU, co-resident)

// ---------------------------------------------------------------------------
__device__ __forceinline__ float block_reduce_sum(float v) {
#pragma unroll
    for (int off = 32; off > 0; off >>= 1) v += __shfl_down(v, off, 64);
    __shared__ float parts[4];
    const int t = threadIdx.x;
    if ((t & 63) == 0) parts[t >> 6] = v;
    __syncthreads();
    float r = 0.f;
    if (t == 0) r = parts[0] + parts[1] + parts[2] + parts[3];
    return r;
}

// ---------------------------------------------------------------------------
// One fused grid: every block computes a 1024x64 dense tile AND a grid-strided
// slice of the sparse term.  Dense math in log2 domain:
//   term_ij = exp(g_i) * exp(d_j - eps) * 2^(-sqrt(zn + qn - 2 zh.qh))
// with zh = L2E*(z+eps), qh = L2E*q.  zm = -2*zh so the pk-FMA chain starting
// from (zn+qn) yields c^2*d^2 directly.
// ---------------------------------------------------------------------------
__global__ __launch_bounds__(NT, 8) void fused_kernel(
    const float* __restrict__ z, const float* __restrict__ q,
    const float* __restrict__ gamma, const float* __restrict__ delta,
    const float* __restrict__ w, const int* __restrict__ si,
    const int* __restrict__ sj, int nnz, float* __restrict__ partial)
{
    __shared__ float4 sqa[TILE];
    __shared__ float4 sqb[TILE];
    __shared__ float2 sqm[TILE];   // {qn, exp(delta - eps)}

    const int t  = threadIdx.x;
    const int id = blockIdx.x;
    const int bi = id >> 7;        // [0,16)
    const int bj = id & (CBLK - 1);
    const int j0 = bj * TILE;

    // ---- stage q tile (issue early) ----
    if (t < TILE) {
        const int j = j0 + t;
        const float4 c = *(const float4*)(q + (size_t)j * 8);
        const float4 d = *(const float4*)(q + (size_t)j * 8 + 4);
        const float4 ca = make_float4(c.x * L2E, c.y * L2E, c.z * L2E, c.w * L2E);
        const float4 cb = make_float4(d.x * L2E, d.y * L2E, d.z * L2E, d.w * L2E);
        sqa[t] = ca;
        sqb[t] = cb;
        const float qn = ca.x*ca.x + ca.y*ca.y + ca.z*ca.z + ca.w*ca.w
                       + cb.x*cb.x + cb.y*cb.y + cb.z*cb.z + cb.w*cb.w;
        sqm[t] = make_float2(qn, __expf(delta[j] - EPSF));
    }

    // ---- my z rows: zm = -2*L2E*(z+eps), zn = |L2E*(z+eps)|^2 ----
    v2f   zm[RPT][4];
    float zn[RPT], eg[RPT];
#pragma unroll
    for (int k = 0; k < RPT; ++k) {
        const int row = bi * ROWS_PB + k * NT + t;
        const float4 a = *(const float4*)(z + (size_t)row * 8);
        const float4 b = *(const float4*)(z + (size_t)row * 8 + 4);
        const float h0 = L2E * (a.x + EPSF), h1 = L2E * (a.y + EPSF);
        const float h2 = L2E * (a.z + EPSF), h3 = L2E * (a.w + EPSF);
        const float h4 = L2E * (b.x + EPSF), h5 = L2E * (b.y + EPSF);
        const float h6 = L2E * (b.z + EPSF), h7 = L2E * (b.w + EPSF);
        zn[k] = h0*h0 + h1*h1 + h2*h2 + h3*h3 + h4*h4 + h5*h5 + h6*h6 + h7*h7;
        zm[k][0] = (v2f){-2.f * h0, -2.f * h1};
        zm[k][1] = (v2f){-2.f * h2, -2.f * h3};
        zm[k][2] = (v2f){-2.f * h4, -2.f * h5};
        zm[k][3] = (v2f){-2.f * h6, -2.f * h7};
        eg[k] = __expf(gamma[row]);
    }

    // ---- sparse slice (latency-bound; overlaps the staging above) ----
    float sacc = 0.f;
    {
        const int stride = NB * NT;
        for (int k = id * NT + t; k < nnz; k += stride) {
            const int i = si[k];
            const int j = sj[k];
            const float4 a = *(const float4*)(z + (size_t)i * 8);
            const float4 b = *(const float4*)(z + (size_t)i * 8 + 4);
            const float4 c = *(const float4*)(q + (size_t)j * 8);
            const float4 d = *(const float4*)(q + (size_t)j * 8 + 4);
            const float d0 = a.x - c.x + EPSF, d1 = a.y - c.y + EPSF;
            const float d2 = a.z - c.z + EPSF, d3 = a.w - c.w + EPSF;
            const float d4 = b.x - d.x + EPSF, d5 = b.y - d.y + EPSF;
            const float d6 = b.z - d.z + EPSF, d7 = b.w - d.w + EPSF;
            float s2 = d0 * d0;
            s2 = fmaf(d1, d1, s2); s2 = fmaf(d2, d2, s2); s2 = fmaf(d3, d3, s2);
            s2 = fmaf(d4, d4, s2); s2 = fmaf(d5, d5, s2); s2 = fmaf(d6, d6, s2);
            s2 = fmaf(d7, d7, s2);
            const float dist = __builtin_amdgcn_sqrtf(s2);
            sacc = fmaf(w[k], gamma[i] + delta[j] - dist, sacc);
        }
    }
    __syncthreads();

    // ---- dense tile ----
    float acc[RPT] = {0.f, 0.f, 0.f, 0.f};
#pragma unroll 2
    for (int r = 0; r < TILE; ++r) {
        const float4 qa = sqa[r];
        const float4 qb = sqb[r];
        const float2 m  = sqm[r];
        const v2f qa0 = (v2f){qa.x, qa.y}, qa1 = (v2f){qa.z, qa.w};
        const v2f qb0 = (v2f){qb.x, qb.y}, qb1 = (v2f){qb.z, qb.w};
#pragma unroll
        for (int k = 0; k < RPT; ++k) {
            v2f a2 = (v2f){zn[k] + m.x, 0.f};
            a2 = __builtin_elementwise_fma(zm[k][0], qa0, a2);
            a2 = __builtin_elementwise_fma(zm[k][1], qa1, a2);
            a2 = __builtin_elementwise_fma(zm[k][2], qb0, a2);
            a2 = __builtin_elementwise_fma(zm[k][3], qb1, a2);
            float d2 = a2.x + a2.y;
            d2 = fmaxf(d2, 0.f);
            const float st = __builtin_amdgcn_sqrtf(d2);     // = L2E * dist
            acc[k] = fmaf(m.y, __builtin_amdgcn_exp2f(-st), acc[k]);
        }
    }

    float s = sacc;
#pragma unroll
    for (int k = 0; k < RPT; ++k) s = fmaf(-eg[k], acc[k], s);
    const float v = block_reduce_sum(s);
    if (t == 0) partial[id] = v;
}

// ---------------------------------------------------------------------------
__global__ __launch_bounds__(256) void reduce_kernel(
    const float* __restrict__ partial, int n, float* __restrict__ out)
{
    float v = 0.f;
    for (int k = threadIdx.x; k < n; k += 256) v += partial[k];
    v = block_reduce_sum(v);
    if (threadIdx.x == 0) out[0] = v;
}

// ---------------------------------------------------------------------------
extern "C" void kernel_launch(void* const* d_in, const int* in_sizes, int n_in,
                              void* d_out, int out_size, void* d_ws, size_t ws_size,
                              hipStream_t stream) {
    const float* z     = (const float*)d_in[0];   // [16384, 8]
    const float* q     = (const float*)d_in[1];   // [8192, 8]
    const float* gamma = (const float*)d_in[2];   // [16384]
    const float* delta = (const float*)d_in[3];   // [8192]
    const float* w     = (const float*)d_in[4];   // [nnz]
    const int*   si    = (const int*)d_in[5];     // [nnz]
    const int*   sj    = (const int*)d_in[6];     // [nnz]
    const int    nnz   = in_sizes[4];

    float* out = (float*)d_out;
    float* ws  = (float*)d_ws;

    fused_kernel<<<NB, NT, 0, stream>>>(z, q, gamma, delta, w, si, sj, nnz, ws);
    reduce_kernel<<<1, 256, 0, stream>>>(ws, NB, out);
}

// Round 4
// 61.750 us; speedup vs baseline: 1.2498x; 1.2498x over previous
//
#include <hip/hip_runtime.h>

#define EPSF 1e-6f
#define L2E  1.44269504088896340736f   // log2(e)

typedef float v2f __attribute__((ext_vector_type(2)));

constexpr int NT      = 256;
constexpr int TILE    = 128;                 // q columns per block
constexpr int NPAIR   = TILE / 2;            // 64 column-pairs
constexpr int QSTRIDE = 20;                  // padded row stride (floats), 16B-aligned
constexpr int RPT     = 4;                   // z rows per thread
constexpr int ROWS_PB = NT * RPT;            // 1024 rows per block
constexpr int RBLK    = 16384 / ROWS_PB;     // 16
constexpr int CBLK    = 8192 / TILE;         // 64
constexpr int NDENSE  = RBLK * CBLK;         // 1024 dense blocks
constexpr int NSPARSE = 1024;                // sparse blocks

// ---------------------------------------------------------------------------
__device__ __forceinline__ float block_reduce_sum(float v) {
#pragma unroll
    for (int off = 32; off > 0; off >>= 1) v += __shfl_down(v, off, 64);
    __shared__ float parts[4];
    const int t = threadIdx.x;
    if ((t & 63) == 0) parts[t >> 6] = v;
    __syncthreads();
    float r = 0.f;
    if (t == 0) r = parts[0] + parts[1] + parts[2] + parts[3];
    return r;
}

// ---------------------------------------------------------------------------
// Dense math, log2 domain, two j-columns packed per v2f:
//   a2 = {qn_j0, qn_j1} + zn  ;  a2 += (-2*zh_d) * {qh_j0[d], qh_j1[d]}  (8 pk_fma)
//   => a2 = L2E^2 * {d2_j0, d2_j1};  term = ed_j * 2^(-sqrt(a2))
// with zh = L2E*(z+eps), qh = L2E*q, ed = exp(delta - eps).
// ---------------------------------------------------------------------------
__global__ __launch_bounds__(NT) void fused_kernel(
    const float* __restrict__ z, const float* __restrict__ q,
    const float* __restrict__ gamma, const float* __restrict__ delta,
    const float* __restrict__ w, const int* __restrict__ si,
    const int* __restrict__ sj, int nnz, float* __restrict__ partial)
{
    const int t  = threadIdx.x;
    const int id = blockIdx.x;

    if (id < NDENSE) {
        // ---------------- dense path ----------------
        __shared__ __align__(16) float sqp[NPAIR][QSTRIDE]; // [rp][2*d+h] = qh pairs
        __shared__ __align__(16) float sqn[NPAIR][2];       // {qn_j0, qn_j1}
        __shared__ __align__(16) float sed[NPAIR][2];       // {ed_j0, ed_j1}

        const int bi = id >> 6;          // id / CBLK
        const int bj = id & (CBLK - 1);
        const int j0 = bj * TILE;

        // stage q tile: column j -> pair slot (t>>1), half (t&1)
        if (t < TILE) {
            const int j  = j0 + t;
            const int rp = t >> 1;
            const int h  = t & 1;
            const float4 c = *(const float4*)(q + (size_t)j * 8);
            const float4 d = *(const float4*)(q + (size_t)j * 8 + 4);
            const float h0 = L2E * c.x, h1 = L2E * c.y, h2 = L2E * c.z, h3 = L2E * c.w;
            const float h4 = L2E * d.x, h5 = L2E * d.y, h6 = L2E * d.z, h7 = L2E * d.w;
            sqp[rp][0  + h] = h0; sqp[rp][2  + h] = h1;
            sqp[rp][4  + h] = h2; sqp[rp][6  + h] = h3;
            sqp[rp][8  + h] = h4; sqp[rp][10 + h] = h5;
            sqp[rp][12 + h] = h6; sqp[rp][14 + h] = h7;
            sqn[rp][h] = h0*h0 + h1*h1 + h2*h2 + h3*h3
                       + h4*h4 + h5*h5 + h6*h6 + h7*h7;
            sed[rp][h] = __expf(delta[j] - EPSF);
        }

        // my z rows: zh = L2E*(z+eps); zm_d = -2*zh_d; zn = |zh|^2
        float zm[RPT][8], zn[RPT], eg[RPT];
#pragma unroll
        for (int k = 0; k < RPT; ++k) {
            const int row = bi * ROWS_PB + k * NT + t;
            const float4 a = *(const float4*)(z + (size_t)row * 8);
            const float4 b = *(const float4*)(z + (size_t)row * 8 + 4);
            const float h0 = L2E * (a.x + EPSF), h1 = L2E * (a.y + EPSF);
            const float h2 = L2E * (a.z + EPSF), h3 = L2E * (a.w + EPSF);
            const float h4 = L2E * (b.x + EPSF), h5 = L2E * (b.y + EPSF);
            const float h6 = L2E * (b.z + EPSF), h7 = L2E * (b.w + EPSF);
            zn[k] = h0*h0 + h1*h1 + h2*h2 + h3*h3 + h4*h4 + h5*h5 + h6*h6 + h7*h7;
            zm[k][0] = -2.f * h0; zm[k][1] = -2.f * h1;
            zm[k][2] = -2.f * h2; zm[k][3] = -2.f * h3;
            zm[k][4] = -2.f * h4; zm[k][5] = -2.f * h5;
            zm[k][6] = -2.f * h6; zm[k][7] = -2.f * h7;
            eg[k] = __expf(gamma[row]);
        }
        __syncthreads();

        v2f acc2[RPT] = {{0.f, 0.f}, {0.f, 0.f}, {0.f, 0.f}, {0.f, 0.f}};
#pragma unroll 2
        for (int rp = 0; rp < NPAIR; ++rp) {
            const float4 p0 = *(const float4*)&sqp[rp][0];   // dims 0,1
            const float4 p1 = *(const float4*)&sqp[rp][4];   // dims 2,3
            const float4 p2 = *(const float4*)&sqp[rp][8];   // dims 4,5
            const float4 p3 = *(const float4*)&sqp[rp][12];  // dims 6,7
            const v2f qn = *(const v2f*)sqn[rp];
            const v2f ed = *(const v2f*)sed[rp];
#pragma unroll
            for (int k = 0; k < RPT; ++k) {
                v2f a2 = qn + (v2f){zn[k], zn[k]};
                a2 = __builtin_elementwise_fma((v2f){zm[k][0], zm[k][0]}, (v2f){p0.x, p0.y}, a2);
                a2 = __builtin_elementwise_fma((v2f){zm[k][1], zm[k][1]}, (v2f){p0.z, p0.w}, a2);
                a2 = __builtin_elementwise_fma((v2f){zm[k][2], zm[k][2]}, (v2f){p1.x, p1.y}, a2);
                a2 = __builtin_elementwise_fma((v2f){zm[k][3], zm[k][3]}, (v2f){p1.z, p1.w}, a2);
                a2 = __builtin_elementwise_fma((v2f){zm[k][4], zm[k][4]}, (v2f){p2.x, p2.y}, a2);
                a2 = __builtin_elementwise_fma((v2f){zm[k][5], zm[k][5]}, (v2f){p2.z, p2.w}, a2);
                a2 = __builtin_elementwise_fma((v2f){zm[k][6], zm[k][6]}, (v2f){p3.x, p3.y}, a2);
                a2 = __builtin_elementwise_fma((v2f){zm[k][7], zm[k][7]}, (v2f){p3.z, p3.w}, a2);
                const float s0 = __builtin_amdgcn_sqrtf(fmaxf(a2.x, 0.f));
                const float s1 = __builtin_amdgcn_sqrtf(fmaxf(a2.y, 0.f));
                const v2f e2 = {__builtin_amdgcn_exp2f(-s0), __builtin_amdgcn_exp2f(-s1)};
                acc2[k] = __builtin_elementwise_fma(ed, e2, acc2[k]);
            }
        }

        float s = 0.f;
#pragma unroll
        for (int k = 0; k < RPT; ++k) s = fmaf(eg[k], acc2[k].x + acc2[k].y, s);
        const float v = block_reduce_sum(-s);
        if (t == 0) partial[id] = v;
    } else {
        // ---------------- sparse path ----------------
        const int sid    = id - NDENSE;
        const int stride = NSPARSE * NT;
        float acc = 0.f;
        for (int k = sid * NT + t; k < nnz; k += stride) {
            const int i = si[k];
            const int j = sj[k];
            const float4 a = *(const float4*)(z + (size_t)i * 8);
            const float4 b = *(const float4*)(z + (size_t)i * 8 + 4);
            const float4 c = *(const float4*)(q + (size_t)j * 8);
            const float4 d = *(const float4*)(q + (size_t)j * 8 + 4);
            const float d0 = a.x - c.x + EPSF, d1 = a.y - c.y + EPSF;
            const float d2 = a.z - c.z + EPSF, d3 = a.w - c.w + EPSF;
            const float d4 = b.x - d.x + EPSF, d5 = b.y - d.y + EPSF;
            const float d6 = b.z - d.z + EPSF, d7 = b.w - d.w + EPSF;
            float s2 = d0 * d0;
            s2 = fmaf(d1, d1, s2); s2 = fmaf(d2, d2, s2); s2 = fmaf(d3, d3, s2);
            s2 = fmaf(d4, d4, s2); s2 = fmaf(d5, d5, s2); s2 = fmaf(d6, d6, s2);
            s2 = fmaf(d7, d7, s2);
            const float dist = __builtin_amdgcn_sqrtf(s2);
            acc = fmaf(w[k], gamma[i] + delta[j] - dist, acc);
        }
        const float v = block_reduce_sum(acc);
        if (t == 0) partial[id] = v;
    }
}

// ---------------------------------------------------------------------------
__global__ __launch_bounds__(256) void reduce_kernel(
    const float* __restrict__ partial, int n, float* __restrict__ out)
{
    float v = 0.f;
    for (int k = threadIdx.x; k < n; k += 256) v += partial[k];
    v = block_reduce_sum(v);
    if (threadIdx.x == 0) out[0] = v;
}

// ---------------------------------------------------------------------------
extern "C" void kernel_launch(void* const* d_in, const int* in_sizes, int n_in,
                              void* d_out, int out_size, void* d_ws, size_t ws_size,
                              hipStream_t stream) {
    const float* z     = (const float*)d_in[0];   // [16384, 8]
    const float* q     = (const float*)d_in[1];   // [8192, 8]
    const float* gamma = (const float*)d_in[2];   // [16384]
    const float* delta = (const float*)d_in[3];   // [8192]
    const float* w     = (const float*)d_in[4];   // [nnz]
    const int*   si    = (const int*)d_in[5];     // [nnz]
    const int*   sj    = (const int*)d_in[6];     // [nnz]
    const int    nnz   = in_sizes[4];

    float* out = (float*)d_out;
    float* ws  = (float*)d_ws;

    fused_kernel<<<NDENSE + NSPARSE, NT, 0, stream>>>(z, q, gamma, delta,
                                                      w, si, sj, nnz, ws);
    reduce_kernel<<<1, 256, 0, stream>>>(ws, NDENSE + NSPARSE, out);
}